// Round 5
// baseline (2614.320 us; speedup 1.0000x reference)
//
#include <hip/hip_runtime.h>
#include <math.h>

#define NN   10000
#define NE   80000
#define NG   64
#define HID  256
#define RBFK 16
#define NDEP 6
#define KA   16
#define KC   6
#define KE   5
#define DE   85
#define CATW 784
#define CATP 832   // padded to multiple of 64

typedef __attribute__((ext_vector_type(8))) short bf16x8;
typedef __attribute__((ext_vector_type(4))) float f32x4;

static __device__ __forceinline__ float silu_f(float v) { return v / (1.0f + expf(-v)); }

static __device__ __forceinline__ unsigned short f2bf(float f) {
  union { float f; unsigned int u; } v; v.f = f;
  unsigned int r = v.u + 0x7fff + ((v.u >> 16) & 1);
  return (unsigned short)(r >> 16);
}
static __device__ __forceinline__ float bf2f(unsigned short h) {
  union { unsigned int u; float f; } v; v.u = ((unsigned int)h) << 16;
  return v.f;
}

static __device__ __forceinline__ void gload16(const void* g, void* l) {
  __builtin_amdgcn_global_load_lds((const __attribute__((address_space(1))) unsigned int*)g,
                                   (__attribute__((address_space(3))) unsigned int*)l, 16, 0, 0);
}

// ---------------- LDS-tiled weight transpose-convert ----------------
__global__ void convw_plain(const float* __restrict__ W, unsigned short* __restrict__ Wt, int K) {
  __shared__ float T[32][65];
  int k0 = blockIdx.x * 32, n0 = blockIdx.y * 64, d = blockIdx.z;
  int tid = threadIdx.x;
  int nn = tid & 63, kr = tid >> 6;
  const float* Wd = W + (size_t)d * K * 256;
#pragma unroll
  for (int i = 0; i < 8; ++i) {
    int k = kr + i * 4;
    T[k][nn] = Wd[(size_t)(k0 + k) * 256 + n0 + nn];
  }
  __syncthreads();
  unsigned short* Wtd = Wt + (size_t)d * 256 * K;
  int kk = tid & 31, nr = tid >> 5;
#pragma unroll
  for (int i = 0; i < 8; ++i) {
    int n = nr + i * 8;
    Wtd[(size_t)(n0 + n) * K + k0 + kk] = f2bf(T[kk][n]);
  }
}

// cat: W [D][784][256] f32 -> Wt [D][512][832] bf16 rows [ro, ro+256)
// permuted k-order: [h_dst 0..511 | e_emb 512..767 | rbf 768..783 | pad..831]
__global__ void convw_cat(const float* __restrict__ W, unsigned short* __restrict__ Wt, int ro) {
  __shared__ float T[32][65];
  int k0 = blockIdx.x * 32, n0 = blockIdx.y * 64, d = blockIdx.z;
  int tid = threadIdx.x;
  int nn = tid & 63, kr = tid >> 6;
  const float* Wd = W + (size_t)d * CATW * 256;
#pragma unroll
  for (int i = 0; i < 8; ++i) {
    int k = k0 + kr + i * 4;
    int ko = (k < 512) ? k : (k < 768 ? k + 16 : (k < 784 ? k - 256 : -1));
    T[kr + i*4][nn] = (ko >= 0) ? Wd[(size_t)ko * 256 + n0 + nn] : 0.f;
  }
  __syncthreads();
  unsigned short* Wtd = Wt + (size_t)d * 512 * CATP;
  int kk = tid & 31, nr = tid >> 5;
#pragma unroll
  for (int i = 0; i < 8; ++i) {
    int n = nr + i * 8;
    Wtd[(size_t)(ro + n0 + n) * CATP + k0 + kk] = f2bf(T[kk][n]);
  }
}

// ---------------- tables (27 blocks) ----------------
__global__ void tables_kernel(const float* __restrict__ atom_W, const float* __restrict__ charge_W,
                              const float* __restrict__ bond_W, const float* __restrict__ fuse_W,
                              const float* __restrict__ fuse_b, const float* __restrict__ lift_W,
                              const float* __restrict__ lift_b,
                              float* __restrict__ tabA, float* __restrict__ tabC,
                              unsigned short* __restrict__ tabE) {
  int r = blockIdx.x, k = threadIdx.x;
  if (r < KA) {
    float s = 0.f;
    for (int d = 0; d < DE; ++d) s += atom_W[r*DE + d] * fuse_W[d*HID + k];
    tabA[r*HID + k] = s + fuse_b[k];
  } else if (r < KA + KC) {
    int rr = r - KA;
    float s = 0.f;
    for (int d = 0; d < DE; ++d) s += charge_W[rr*DE + d] * fuse_W[(DE + d)*HID + k];
    tabC[rr*HID + k] = s;
  } else {
    int rr = r - KA - KC;
    float s = 0.f;
    for (int d = 0; d < DE; ++d) s += bond_W[rr*DE + d] * lift_W[d*HID + k];
    tabE[rr*HID + k] = f2bf(s + lift_b[k]);
  }
}

// ---------------- node / edge init ----------------
__global__ void node_init_kernel(const float* __restrict__ a_t, const float* __restrict__ c_t,
                                 const float* __restrict__ g_a, const float* __restrict__ g_c,
                                 const float* __restrict__ x_t, const float* __restrict__ tabA,
                                 const float* __restrict__ tabC, float* __restrict__ h,
                                 unsigned short* __restrict__ hbf, float* __restrict__ x) {
  int n = blockIdx.x;
  __shared__ int s_ia, s_ic;
  if (threadIdx.x == 0) {
    float best = -1e30f; int bi = 0;
    for (int j = 0; j < KA; ++j) {
      float v = logf(fmaxf(a_t[n*KA + j], 1e-12f)) + g_a[n*KA + j];
      if (v > best) { best = v; bi = j; }
    }
    s_ia = bi;
  }
  if (threadIdx.x == 1) {
    float best = -1e30f; int bi = 0;
    for (int j = 0; j < KC; ++j) {
      float v = logf(fmaxf(c_t[n*KC + j], 1e-12f)) + g_c[n*KC + j];
      if (v > best) { best = v; bi = j; }
    }
    s_ic = bi;
  }
  __syncthreads();
  int k = threadIdx.x;
  float v = tabA[s_ia*HID + k] + tabC[s_ic*HID + k];
  h[n*HID + k] = v;
  hbf[n*HID + k] = f2bf(v);
  if (k < 3) x[n*3 + k] = x_t[n*3 + k];
}

__global__ void edge_init_kernel(const float* __restrict__ e_t, const float* __restrict__ g_e,
                                 int* __restrict__ ie) {
  int e = blockIdx.x * blockDim.x + threadIdx.x;
  if (e >= NE) return;
  float best = -1e30f; int bi = 0;
  for (int j = 0; j < KE; ++j) {
    float v = logf(fmaxf(e_t[e*KE + j], 1e-12f)) + g_e[e*KE + j];
    if (v > best) { best = v; bi = j; }
  }
  ie[e] = bi;
}

// ---------------- CSR build ----------------
__global__ void hist_kernel(const int* __restrict__ dst, int* __restrict__ deg) {
  int e = blockIdx.x * 256 + threadIdx.x;
  if (e < NE) atomicAdd(&deg[dst[e]], 1);
}

__global__ void scan_kernel(const int* __restrict__ deg, int* __restrict__ rowstart,
                            int* __restrict__ cursor) {
  __shared__ int tmp[1024];
  int t = threadIdx.x;
  int base = t * 10;
  int local[10];
  int s = 0;
#pragma unroll
  for (int i = 0; i < 10; ++i) { local[i] = deg[base + i]; s += local[i]; }
  tmp[t] = s;
  __syncthreads();
  for (int off = 1; off < 1024; off <<= 1) {
    int v = (t >= off) ? tmp[t - off] : 0;
    __syncthreads();
    tmp[t] += v;
    __syncthreads();
  }
  int run = (t == 0) ? 0 : tmp[t - 1];
#pragma unroll
  for (int i = 0; i < 10; ++i) {
    rowstart[base + i] = run; cursor[base + i] = run; run += local[i];
  }
  if (t == 1023) rowstart[10240] = run;
}

__global__ void fill_kernel(const int* __restrict__ dst, int* __restrict__ cursor,
                            int* __restrict__ eids) {
  int e = blockIdx.x * 256 + threadIdx.x;
  if (e >= NE) return;
  int pos = atomicAdd(&cursor[dst[e]], 1);
  eids[pos] = e;
}

__global__ void sortrows_kernel(const int* __restrict__ rowstart, int* __restrict__ eids) {
  int n = blockIdx.x * 256 + threadIdx.x;
  if (n >= NN) return;
  int s = rowstart[n], e = rowstart[n + 1];
  for (int i = s + 1; i < e; ++i) {
    int v = eids[i]; int j = i - 1;
    while (j >= s && eids[j] > v) { eids[j + 1] = eids[j]; --j; }
    eids[j + 1] = v;
  }
}

// ---------------- per-depth: rij + rbf(bf16) ----------------
__global__ void rbf_kernel(const float* __restrict__ x, const int* __restrict__ srcp,
                           const int* __restrict__ dstp, float* __restrict__ rij,
                           unsigned short* __restrict__ rbfb) {
  int e = blockIdx.x * blockDim.x + threadIdx.x;
  if (e >= NE) return;
  int s = srcp[e], d = dstp[e];
  float r0 = x[d*3+0] - x[s*3+0];
  float r1 = x[d*3+1] - x[s*3+1];
  float r2 = x[d*3+2] - x[s*3+2];
  rij[e*3+0] = r0; rij[e*3+1] = r1; rij[e*3+2] = r2;
  float dist = sqrtf(r0*r0 + r1*r1 + r2*r2);
#pragma unroll
  for (int k = 0; k < RBFK; ++k) {
    float c = (10.0f/15.0f) * (float)k;
    float z = (dist - c) / (0.625f + 1e-12f);
    rbfb[e*RBFK + k] = f2bf(expf(-0.5f * z * z));
  }
}

// ---------------- MFMA bf16 GEMM (gload_lds, BK=64, XOR swizzle, 2-phase dbuf pipeline) ----------------
// MODE 0: A bf16 [M][256]
// MODE 1: A = cat(e) = [h[dst] | h[src] | tabE[ie] | rbf | pad] (Kp=832, N=512 dual-output)
// MODE 2: A = [hbf | pmbf] (Kp=512)
// GATE:   no C store; gate[row] += sum_col silu(acc+b1[col]) * gw2[col]
template<int MODE, bool SILU, bool GATE>
__global__ __launch_bounds__(256) void mfma_gemm(
    const unsigned short* __restrict__ A, const unsigned short* __restrict__ A2,
    const unsigned short* __restrict__ Wt,
    const float* __restrict__ bias, const float* __restrict__ bias2,
    unsigned short* __restrict__ C, unsigned short* __restrict__ C2,
    int M, int Kp,
    const unsigned short* __restrict__ hbf, const unsigned short* __restrict__ tabE,
    const int* __restrict__ srcp, const int* __restrict__ dstp, const int* __restrict__ iep,
    const unsigned short* __restrict__ rbfb, const unsigned short* __restrict__ zpad,
    const float* __restrict__ gw2, float* __restrict__ gout) {
  __shared__ unsigned short As[2][128 * 64];   // [128][64] XOR-swizzled, double-buffered
  __shared__ unsigned short Bs[2][128 * 64];
  const int tid = threadIdx.x;
  const int bn = blockIdx.x * 128;
  const int bm = blockIdx.y * 128;
  const int lane = tid & 63;
  const int w = tid >> 6;
  const int wr = w >> 1, wc = w & 1;
  const int subrow = lane >> 3;                 // 0..7
  const int kd = 8 * ((lane & 7) ^ subrow);     // pre-swizzled data k-offset (elems)

  // per-thread staged rows (4 issues per wave)
  const unsigned short* baseB[4];
  const unsigned short* baseA[4];
  const unsigned short* baseA2[4];
  const unsigned short* baseE[4];
  const unsigned short* baseR[4];
#pragma unroll
  for (int q = 0; q < 4; ++q) {
    int r = w * 32 + q * 8 + subrow;
    baseB[q] = Wt + (size_t)(bn + r) * Kp;
    int m = bm + r;
    int mc = (m < M) ? m : (M - 1);
    if (MODE == 1) {
      baseA[q]  = hbf + (size_t)dstp[m] * 256;
      baseA2[q] = hbf + (size_t)srcp[m] * 256;
      baseE[q]  = tabE + (size_t)iep[m] * 256;
      baseR[q]  = rbfb + (size_t)m * RBFK;
    } else {
      baseA[q]  = A + (size_t)mc * 256;
      baseA2[q] = (MODE == 2) ? (A2 + (size_t)mc * 256) : nullptr;
    }
  }

  const int nt = Kp >> 6;

  auto stage = [&](int buf, int k0) {
#pragma unroll
    for (int q = 0; q < 4; ++q) {
      char* ldsA = (char*)&As[buf][0] + w * 4096 + q * 1024;
      char* ldsB = (char*)&Bs[buf][0] + w * 4096 + q * 1024;
      const unsigned short* gp;
      if (MODE == 0) {
        gp = baseA[q] + k0 + kd;
      } else if (MODE == 1) {
        if (k0 < 256)      gp = baseA[q] + k0 + kd;
        else if (k0 < 512) gp = baseA2[q] + (k0 - 256) + kd;
        else if (k0 < 768) gp = baseE[q] + (k0 - 512) + kd;
        else               gp = (kd < RBFK) ? (baseR[q] + kd) : zpad;
      } else {
        gp = (k0 < 256) ? (baseA[q] + k0 + kd) : (baseA2[q] + (k0 - 256) + kd);
      }
      gload16(gp, ldsA);
      gload16(baseB[q] + k0 + kd, ldsB);
    }
  };

  f32x4 acc[4][4] = {};

  stage(0, 0);
  __syncthreads();                       // drain prologue stage
  for (int t = 0; t < nt; ++t) {
    if (t + 1 < nt) stage((t + 1) & 1, (t + 1) << 6);   // prefetch flies under compute
    const char* Ab = (const char*)&As[t & 1][0];
    const char* Bb = (const char*)&Bs[t & 1][0];
#pragma unroll
    for (int ks = 0; ks < 2; ++ks) {
      const int kb = (ks * 64 + ((lane >> 4) << 4)) ^ ((lane & 7) << 4);
      bf16x8 af[4], bfv[4];
#pragma unroll
      for (int i = 0; i < 4; ++i)
        af[i] = *(const bf16x8*)(Ab + (wr*64 + i*16 + (lane & 15)) * 128 + kb);
#pragma unroll
      for (int j = 0; j < 4; ++j)
        bfv[j] = *(const bf16x8*)(Bb + (wc*64 + j*16 + (lane & 15)) * 128 + kb);
#pragma unroll
      for (int i = 0; i < 4; ++i)
#pragma unroll
        for (int j = 0; j < 4; ++j)
          acc[i][j] = __builtin_amdgcn_mfma_f32_16x16x32_bf16(af[i], bfv[j], acc[i][j], 0, 0, 0);
    }
    __syncthreads();                     // drains prefetch + guards dbuf reuse
  }

  if (GATE) {
    float bcol[4], wcol[4];
#pragma unroll
    for (int j = 0; j < 4; ++j) {
      int col = bn + wc*64 + j*16 + (lane & 15);
      bcol[j] = bias[col];
      wcol[j] = gw2[col];
    }
#pragma unroll
    for (int i = 0; i < 4; ++i) {
#pragma unroll
      for (int q = 0; q < 4; ++q) {
        float lsum = 0.f;
#pragma unroll
        for (int j = 0; j < 4; ++j)
          lsum += silu_f(acc[i][j][q] + bcol[j]) * wcol[j];
        lsum += __shfl_xor(lsum, 1, 64);
        lsum += __shfl_xor(lsum, 2, 64);
        lsum += __shfl_xor(lsum, 4, 64);
        lsum += __shfl_xor(lsum, 8, 64);
        if ((lane & 15) == 0) {
          int row = bm + wr*64 + i*16 + ((lane >> 4) << 2) + q;
          if (row < M) atomicAdd(&gout[row], lsum);
        }
      }
    }
    return;
  }

  const float* biasw = bias;
  unsigned short* Cw = C;
  int cb = bn;
  if (MODE == 1 && bn >= 256) { biasw = bias2; Cw = C2; cb = bn - 256; }

  const int colbase = cb + wc*64 + (lane & 15);
#pragma unroll
  for (int j = 0; j < 4; ++j) {
    int col = colbase + j*16;
    float bv = biasw[col];
#pragma unroll
    for (int i = 0; i < 4; ++i) {
      int row0 = bm + wr*64 + i*16 + (lane >> 4) * 4;
#pragma unroll
      for (int q = 0; q < 4; ++q) {
        int row = row0 + q;
        if (row < M) {
          float v = acc[i][j][q] + bv;
          if (SILU) v = silu_f(v);
          Cw[(size_t)row*256 + col] = f2bf(v);
        }
      }
    }
  }
}

// ---------------- CSR gather: pm_sum (bf16 out) + dx + x update ----------------
__global__ void gather_pm_dx(const unsigned short* __restrict__ pm, const float* __restrict__ gate,
                             const float* __restrict__ rij, const int* __restrict__ rowstart,
                             const int* __restrict__ eids, const float* __restrict__ gb2,
                             unsigned short* __restrict__ pmbf, float* __restrict__ x) {
  int n = blockIdx.x, k = threadIdx.x;
  int s = rowstart[n], e1 = rowstart[n + 1];
  float acc = 0.f, dx = 0.f;
  float b2 = gb2[0];
  for (int t = s; t < e1; ++t) {
    int e = eids[t];
    acc += bf2f(pm[(size_t)e*HID + k]);
    if (k < 3) dx += rij[e*3 + k] * (gate[e] + b2);
  }
  pmbf[(size_t)n*HID + k] = f2bf(acc);
  if (k < 3) x[n*3 + k] += dx;
}

// ---------------- LayerNorm(h + u) ----------------
__global__ void ln_kernel(float* __restrict__ h, unsigned short* __restrict__ hbf,
                          const unsigned short* __restrict__ u,
                          const float* __restrict__ g, const float* __restrict__ b) {
  int n = blockIdx.x;
  int k = threadIdx.x;
  int lane = k & 63, wv = k >> 6;
  float z = h[(size_t)n*HID + k] + bf2f(u[(size_t)n*HID + k]);
  __shared__ float red[4];
  __shared__ float s_mu, s_rstd;
  float s = z;
#pragma unroll
  for (int off = 32; off > 0; off >>= 1) s += __shfl_down(s, off, 64);
  if (lane == 0) red[wv] = s;
  __syncthreads();
  if (k == 0) s_mu = (red[0] + red[1] + red[2] + red[3]) * (1.0f/HID);
  __syncthreads();
  float d = z - s_mu;
  float s2 = d * d;
#pragma unroll
  for (int off = 32; off > 0; off >>= 1) s2 += __shfl_down(s2, off, 64);
  if (lane == 0) red[wv] = s2;
  __syncthreads();
  if (k == 0) s_rstd = 1.0f / sqrtf((red[0] + red[1] + red[2] + red[3]) * (1.0f/HID) + 1e-5f);
  __syncthreads();
  float o = d * s_rstd * g[k] + b[k];
  h[(size_t)n*HID + k] = o;
  hbf[(size_t)n*HID + k] = f2bf(o);
}

// ---------------- readout ----------------
__global__ void graph_acc_kernel(const float* __restrict__ h, const int* __restrict__ ng,
                                 float* __restrict__ hg, float* __restrict__ cnt) {
  int n = blockIdx.x, k = threadIdx.x;
  int g = ng[n];
  atomicAdd(&hg[(size_t)g*HID + k], h[(size_t)n*HID + k]);
  if (k == 0) atomicAdd(&cnt[g], 1.0f);
}

__global__ void head_kernel(const float* __restrict__ hg, const float* __restrict__ cnt,
                            const float* __restrict__ head_W, const float* __restrict__ head_b,
                            float* __restrict__ out) {
  int g = threadIdx.x;
  if (g >= NG) return;
  float dot = 0.f;
  for (int k = 0; k < HID; ++k) dot += hg[(size_t)g*HID + k] * head_W[k];
  float c = fmaxf(cnt[g], 1.0f);
  float v = (dot / c + head_b[0]) * 0.5f;
  out[g] = 1.0f / (1.0f + expf(-v));
}

extern "C" void kernel_launch(void* const* d_in, const int* in_sizes, int n_in,
                              void* d_out, int out_size, void* d_ws, size_t ws_size,
                              hipStream_t stream) {
  (void)in_sizes; (void)n_in; (void)out_size; (void)ws_size;
  const float* a_t      = (const float*)d_in[0];
  const float* c_t      = (const float*)d_in[1];
  const float* e_t      = (const float*)d_in[2];
  const float* x_t      = (const float*)d_in[3];
  const float* g_a      = (const float*)d_in[4];
  const float* g_c      = (const float*)d_in[5];
  const float* g_e      = (const float*)d_in[6];
  const float* atom_W   = (const float*)d_in[7];
  const float* charge_W = (const float*)d_in[8];
  const float* bond_W   = (const float*)d_in[9];
  const float* fuse_W   = (const float*)d_in[10];
  const float* fuse_b   = (const float*)d_in[11];
  const float* lift_W   = (const float*)d_in[12];
  const float* lift_b   = (const float*)d_in[13];
  const float* phim_W1  = (const float*)d_in[14];
  const float* phim_b1  = (const float*)d_in[15];
  const float* phim_W2  = (const float*)d_in[16];
  const float* phim_b2  = (const float*)d_in[17];
  const float* phix_W1  = (const float*)d_in[18];
  const float* phix_b1  = (const float*)d_in[19];
  const float* phix_W2  = (const float*)d_in[20];
  const float* phix_b2  = (const float*)d_in[21];
  const float* psim_W1  = (const float*)d_in[22];
  const float* psim_b1  = (const float*)d_in[23];
  const float* psim_W2  = (const float*)d_in[24];
  const float* psim_b2  = (const float*)d_in[25];
  const float* updh_W1  = (const float*)d_in[26];
  const float* updh_b1  = (const float*)d_in[27];
  const float* updh_W2  = (const float*)d_in[28];
  const float* updh_b2  = (const float*)d_in[29];
  const float* ln_g     = (const float*)d_in[30];
  const float* ln_b     = (const float*)d_in[31];
  const float* head_W   = (const float*)d_in[32];
  const float* head_b   = (const float*)d_in[33];
  const int*   src      = (const int*)d_in[34];
  const int*   dst      = (const int*)d_in[35];
  const int*   ngraph   = (const int*)d_in[36];
  float* out = (float*)d_out;

  char* p = (char*)d_ws;
  auto carve = [&](size_t bytes) -> char* {
    char* r = p; p += (bytes + 255) & ~(size_t)255; return r;
  };
  float*          h     = (float*)carve((size_t)NN*HID*4);
  unsigned short* hbf   = (unsigned short*)carve((size_t)NN*HID*2);
  float*          xpos  = (float*)carve((size_t)NN*3*4);
  int*            ie    = (int*)carve((size_t)NE*4);
  float*          tabA  = (float*)carve((size_t)KA*HID*4);
  float*          tabC  = (float*)carve((size_t)KC*HID*4);
  unsigned short* tabE  = (unsigned short*)carve((size_t)KE*HID*2);
  unsigned short* rbfb  = (unsigned short*)carve((size_t)NE*RBFK*2);
  float*          rij   = (float*)carve((size_t)NE*3*4);
  float*          gate  = (float*)carve((size_t)NE*4);
  unsigned short* pmbf  = (unsigned short*)carve((size_t)NN*HID*2);
  unsigned short* zpad  = (unsigned short*)carve(256);
  size_t hg_bytes = (size_t)NG*HID*4 + (size_t)NG*4;
  float*          hg    = (float*)carve(hg_bytes);
  float*          cnt   = hg + (size_t)NG*HID;
  unsigned short* buf0  = (unsigned short*)carve((size_t)NE*HID*2);
  unsigned short* buf1  = (unsigned short*)carve((size_t)NE*HID*2);
  unsigned short* buf2  = (unsigned short*)carve((size_t)NE*HID*2);
  // CSR
  int* deg      = (int*)carve(10240*4);
  int* cursor   = (int*)carve(10240*4);
  int* rowstart = (int*)carve(10241*4);
  int* eids     = (int*)carve((size_t)NE*4);
  // transposed bf16 weights
  unsigned short* wCat   = (unsigned short*)carve((size_t)NDEP*512*CATP*2);
  unsigned short* wPhim2 = (unsigned short*)carve((size_t)NDEP*HID*HID*2);
  unsigned short* wPhix1 = (unsigned short*)carve((size_t)NDEP*HID*HID*2);
  unsigned short* wPsim2 = (unsigned short*)carve((size_t)NDEP*HID*HID*2);
  unsigned short* wUpd1  = (unsigned short*)carve((size_t)NDEP*HID*512*2);
  unsigned short* wUpd2  = (unsigned short*)carve((size_t)NDEP*HID*HID*2);

  // ---- weight conversion ----
  convw_cat<<<dim3(CATP/32, 4, NDEP), 256, 0, stream>>>(phim_W1, wCat, 0);
  convw_cat<<<dim3(CATP/32, 4, NDEP), 256, 0, stream>>>(psim_W1, wCat, 256);
  convw_plain<<<dim3(8, 4, NDEP), 256, 0, stream>>>(phim_W2, wPhim2, 256);
  convw_plain<<<dim3(8, 4, NDEP), 256, 0, stream>>>(phix_W1, wPhix1, 256);
  convw_plain<<<dim3(8, 4, NDEP), 256, 0, stream>>>(psim_W2, wPsim2, 256);
  convw_plain<<<dim3(8, 4, NDEP), 256, 0, stream>>>(updh_W2, wUpd2, 256);
  convw_plain<<<dim3(16, 4, NDEP), 256, 0, stream>>>(updh_W1, wUpd1, 512);
  hipMemsetAsync(zpad, 0, 256, stream);

  tables_kernel<<<KA + KC + KE, 256, 0, stream>>>(atom_W, charge_W, bond_W, fuse_W, fuse_b,
                                                  lift_W, lift_b, tabA, tabC, tabE);
  node_init_kernel<<<NN, 256, 0, stream>>>(a_t, c_t, g_a, g_c, x_t, tabA, tabC, h, hbf, xpos);
  edge_init_kernel<<<(NE + 255)/256, 256, 0, stream>>>(e_t, g_e, ie);

  // ---- CSR build ----
  hipMemsetAsync(deg, 0, 10240*4, stream);
  hist_kernel<<<(NE + 255)/256, 256, 0, stream>>>(dst, deg);
  scan_kernel<<<1, 1024, 0, stream>>>(deg, rowstart, cursor);
  fill_kernel<<<(NE + 255)/256, 256, 0, stream>>>(dst, cursor, eids);
  sortrows_kernel<<<(NN + 255)/256, 256, 0, stream>>>(rowstart, eids);

  dim3 gridCat(4, NE/128);
  dim3 gridE(2, NE/128);
  dim3 gridN(2, (NN + 127)/128);

  for (int d = 0; d < NDEP; ++d) {
    const float* pb1m = phim_b1 + (size_t)d*HID;
    const float* pb2m = phim_b2 + (size_t)d*HID;
    const float* pxb1 = phix_b1 + (size_t)d*HID;
    const float* pxW2 = phix_W2 + (size_t)d*HID;
    const float* pxb2 = phix_b2 + (size_t)d;
    const float* psb1 = psim_b1 + (size_t)d*HID;
    const float* psb2 = psim_b2 + (size_t)d*HID;
    const float* pub1 = updh_b1 + (size_t)d*HID;
    const float* pub2 = updh_b2 + (size_t)d*HID;

    rbf_kernel<<<(NE + 255)/256, 256, 0, stream>>>(xpos, src, dst, rij, rbfb);

    // c1 (buf0), ps1 (buf1) = silu(cat @ [phim_W1 ; psim_W1] + b)
    mfma_gemm<1, true, false><<<gridCat, 256, 0, stream>>>(
        nullptr, nullptr, wCat + (size_t)d*512*CATP, pb1m, psb1, buf0, buf1, NE, CATP,
        hbf, tabE, src, dst, ie, rbfb, zpad, nullptr, nullptr);
    // m (buf2) = silu(c1 @ phim_W2 + b2)
    mfma_gemm<0, true, false><<<gridE, 256, 0, stream>>>(
        buf0, nullptr, wPhim2 + (size_t)d*HID*HID, pb2m, nullptr, buf2, nullptr, NE, HID,
        nullptr, nullptr, nullptr, nullptr, nullptr, nullptr, zpad, nullptr, nullptr);
    // pm (buf0) = silu(ps1 @ psim_W2 + b2)
    mfma_gemm<0, true, false><<<gridE, 256, 0, stream>>>(
        buf1, nullptr, wPsim2 + (size_t)d*HID*HID, psb2, nullptr, buf0, nullptr, NE, HID,
        nullptr, nullptr, nullptr, nullptr, nullptr, nullptr, zpad, nullptr, nullptr);
    // gate = silu(m @ phix_W1 + b1) @ phix_W2   (bias b2 added at use)
    hipMemsetAsync(gate, 0, (size_t)NE*4, stream);
    mfma_gemm<0, false, true><<<gridE, 256, 0, stream>>>(
        buf2, nullptr, wPhix1 + (size_t)d*HID*HID, pxb1, nullptr, nullptr, nullptr, NE, HID,
        nullptr, nullptr, nullptr, nullptr, nullptr, nullptr, zpad, pxW2, gate);
    // pm_sum -> pmbf ; x += dx
    gather_pm_dx<<<NN, 256, 0, stream>>>(buf0, gate, rij, rowstart, eids, pxb2, pmbf, xpos);
    // u1 (buf1) = silu([h, pm] @ updh_W1 + b1)
    mfma_gemm<2, true, false><<<gridN, 256, 0, stream>>>(
        hbf, pmbf, wUpd1 + (size_t)d*HID*512, pub1, nullptr, buf1, nullptr, NN, 512,
        nullptr, nullptr, nullptr, nullptr, nullptr, nullptr, zpad, nullptr, nullptr);
    // u (buf2) = u1 @ updh_W2 + b2
    mfma_gemm<0, false, false><<<gridN, 256, 0, stream>>>(
        buf1, nullptr, wUpd2 + (size_t)d*HID*HID, pub2, nullptr, buf2, nullptr, NN, HID,
        nullptr, nullptr, nullptr, nullptr, nullptr, nullptr, zpad, nullptr, nullptr);
    ln_kernel<<<NN, 256, 0, stream>>>(h, hbf, buf2, ln_g + (size_t)d*HID, ln_b + (size_t)d*HID);
  }

  hipMemsetAsync(hg, 0, hg_bytes, stream);
  graph_acc_kernel<<<NN, 256, 0, stream>>>(h, ngraph, hg, cnt);
  head_kernel<<<1, 64, 0, stream>>>(hg, cnt, head_W, head_b, out);
}

// Round 6
// 2105.557 us; speedup vs baseline: 1.2416x; 1.2416x over previous
//
#include <hip/hip_runtime.h>
#include <math.h>

#define NN   10000
#define NE   80000
#define NG   64
#define HID  256
#define RBFK 16
#define NDEP 6
#define KA   16
#define KC   6
#define KE   5
#define DE   85
#define CATW 784
#define CATP 832   // padded to multiple of 64

typedef __attribute__((ext_vector_type(8))) short bf16x8;
typedef __attribute__((ext_vector_type(4))) float f32x4;

static __device__ __forceinline__ float silu_f(float v) { return v / (1.0f + expf(-v)); }

static __device__ __forceinline__ unsigned short f2bf(float f) {
  union { float f; unsigned int u; } v; v.f = f;
  unsigned int r = v.u + 0x7fff + ((v.u >> 16) & 1);
  return (unsigned short)(r >> 16);
}
static __device__ __forceinline__ float bf2f(unsigned short h) {
  union { unsigned int u; float f; } v; v.u = ((unsigned int)h) << 16;
  return v.f;
}

static __device__ __forceinline__ void gload16(const void* g, void* l) {
  __builtin_amdgcn_global_load_lds((const __attribute__((address_space(1))) unsigned int*)g,
                                   (__attribute__((address_space(3))) unsigned int*)l, 16, 0, 0);
}

// ---------------- LDS-tiled weight transpose-convert ----------------
__global__ void convw_plain(const float* __restrict__ W, unsigned short* __restrict__ Wt, int K) {
  __shared__ float T[32][65];
  int k0 = blockIdx.x * 32, n0 = blockIdx.y * 64, d = blockIdx.z;
  int tid = threadIdx.x;
  int nn = tid & 63, kr = tid >> 6;
  const float* Wd = W + (size_t)d * K * 256;
#pragma unroll
  for (int i = 0; i < 8; ++i) {
    int k = kr + i * 4;
    T[k][nn] = Wd[(size_t)(k0 + k) * 256 + n0 + nn];
  }
  __syncthreads();
  unsigned short* Wtd = Wt + (size_t)d * 256 * K;
  int kk = tid & 31, nr = tid >> 5;
#pragma unroll
  for (int i = 0; i < 8; ++i) {
    int n = nr + i * 8;
    Wtd[(size_t)(n0 + n) * K + k0 + kk] = f2bf(T[kk][n]);
  }
}

// cat: W [D][784][256] f32 -> Wt [D][512][832] bf16 rows [ro, ro+256)
// permuted k-order: [h_dst 0..511 | e_emb 512..767 | rbf 768..783 | pad..831]
__global__ void convw_cat(const float* __restrict__ W, unsigned short* __restrict__ Wt, int ro) {
  __shared__ float T[32][65];
  int k0 = blockIdx.x * 32, n0 = blockIdx.y * 64, d = blockIdx.z;
  int tid = threadIdx.x;
  int nn = tid & 63, kr = tid >> 6;
  const float* Wd = W + (size_t)d * CATW * 256;
#pragma unroll
  for (int i = 0; i < 8; ++i) {
    int k = k0 + kr + i * 4;
    int ko = (k < 512) ? k : (k < 768 ? k + 16 : (k < 784 ? k - 256 : -1));
    T[kr + i*4][nn] = (ko >= 0) ? Wd[(size_t)ko * 256 + n0 + nn] : 0.f;
  }
  __syncthreads();
  unsigned short* Wtd = Wt + (size_t)d * 512 * CATP;
  int kk = tid & 31, nr = tid >> 5;
#pragma unroll
  for (int i = 0; i < 8; ++i) {
    int n = nr + i * 8;
    Wtd[(size_t)(ro + n0 + n) * CATP + k0 + kk] = f2bf(T[kk][n]);
  }
}

// ---------------- tables (27 blocks) ----------------
__global__ void tables_kernel(const float* __restrict__ atom_W, const float* __restrict__ charge_W,
                              const float* __restrict__ bond_W, const float* __restrict__ fuse_W,
                              const float* __restrict__ fuse_b, const float* __restrict__ lift_W,
                              const float* __restrict__ lift_b,
                              float* __restrict__ tabA, float* __restrict__ tabC,
                              unsigned short* __restrict__ tabE) {
  int r = blockIdx.x, k = threadIdx.x;
  if (r < KA) {
    float s = 0.f;
    for (int d = 0; d < DE; ++d) s += atom_W[r*DE + d] * fuse_W[d*HID + k];
    tabA[r*HID + k] = s + fuse_b[k];
  } else if (r < KA + KC) {
    int rr = r - KA;
    float s = 0.f;
    for (int d = 0; d < DE; ++d) s += charge_W[rr*DE + d] * fuse_W[(DE + d)*HID + k];
    tabC[rr*HID + k] = s;
  } else {
    int rr = r - KA - KC;
    float s = 0.f;
    for (int d = 0; d < DE; ++d) s += bond_W[rr*DE + d] * lift_W[d*HID + k];
    tabE[rr*HID + k] = f2bf(s + lift_b[k]);
  }
}

// ---------------- node / edge init ----------------
__global__ void node_init_kernel(const float* __restrict__ a_t, const float* __restrict__ c_t,
                                 const float* __restrict__ g_a, const float* __restrict__ g_c,
                                 const float* __restrict__ x_t, const float* __restrict__ tabA,
                                 const float* __restrict__ tabC, float* __restrict__ h,
                                 unsigned short* __restrict__ hbf, float* __restrict__ x) {
  int n = blockIdx.x;
  __shared__ int s_ia, s_ic;
  if (threadIdx.x == 0) {
    float best = -1e30f; int bi = 0;
    for (int j = 0; j < KA; ++j) {
      float v = logf(fmaxf(a_t[n*KA + j], 1e-12f)) + g_a[n*KA + j];
      if (v > best) { best = v; bi = j; }
    }
    s_ia = bi;
  }
  if (threadIdx.x == 1) {
    float best = -1e30f; int bi = 0;
    for (int j = 0; j < KC; ++j) {
      float v = logf(fmaxf(c_t[n*KC + j], 1e-12f)) + g_c[n*KC + j];
      if (v > best) { best = v; bi = j; }
    }
    s_ic = bi;
  }
  __syncthreads();
  int k = threadIdx.x;
  float v = tabA[s_ia*HID + k] + tabC[s_ic*HID + k];
  h[n*HID + k] = v;
  hbf[n*HID + k] = f2bf(v);
  if (k < 3) x[n*3 + k] = x_t[n*3 + k];
}

__global__ void edge_init_kernel(const float* __restrict__ e_t, const float* __restrict__ g_e,
                                 int* __restrict__ ie) {
  int e = blockIdx.x * blockDim.x + threadIdx.x;
  if (e >= NE) return;
  float best = -1e30f; int bi = 0;
  for (int j = 0; j < KE; ++j) {
    float v = logf(fmaxf(e_t[e*KE + j], 1e-12f)) + g_e[e*KE + j];
    if (v > best) { best = v; bi = j; }
  }
  ie[e] = bi;
}

// ---------------- CSR build ----------------
__global__ void hist_kernel(const int* __restrict__ dst, int* __restrict__ deg) {
  int e = blockIdx.x * 256 + threadIdx.x;
  if (e < NE) atomicAdd(&deg[dst[e]], 1);
}

__global__ void scan_kernel(const int* __restrict__ deg, int* __restrict__ rowstart,
                            int* __restrict__ cursor) {
  __shared__ int tmp[1024];
  int t = threadIdx.x;
  int base = t * 10;
  int local[10];
  int s = 0;
#pragma unroll
  for (int i = 0; i < 10; ++i) { local[i] = deg[base + i]; s += local[i]; }
  tmp[t] = s;
  __syncthreads();
  for (int off = 1; off < 1024; off <<= 1) {
    int v = (t >= off) ? tmp[t - off] : 0;
    __syncthreads();
    tmp[t] += v;
    __syncthreads();
  }
  int run = (t == 0) ? 0 : tmp[t - 1];
#pragma unroll
  for (int i = 0; i < 10; ++i) {
    rowstart[base + i] = run; cursor[base + i] = run; run += local[i];
  }
  if (t == 1023) rowstart[10240] = run;
}

__global__ void fill_kernel(const int* __restrict__ dst, int* __restrict__ cursor,
                            int* __restrict__ eids) {
  int e = blockIdx.x * 256 + threadIdx.x;
  if (e >= NE) return;
  int pos = atomicAdd(&cursor[dst[e]], 1);
  eids[pos] = e;
}

__global__ void sortrows_kernel(const int* __restrict__ rowstart, int* __restrict__ eids) {
  int n = blockIdx.x * 256 + threadIdx.x;
  if (n >= NN) return;
  int s = rowstart[n], e = rowstart[n + 1];
  for (int i = s + 1; i < e; ++i) {
    int v = eids[i]; int j = i - 1;
    while (j >= s && eids[j] > v) { eids[j + 1] = eids[j]; --j; }
    eids[j + 1] = v;
  }
}

// ---------------- per-depth: rij + rbf(bf16) ----------------
__global__ void rbf_kernel(const float* __restrict__ x, const int* __restrict__ srcp,
                           const int* __restrict__ dstp, float* __restrict__ rij,
                           unsigned short* __restrict__ rbfb) {
  int e = blockIdx.x * blockDim.x + threadIdx.x;
  if (e >= NE) return;
  int s = srcp[e], d = dstp[e];
  float r0 = x[d*3+0] - x[s*3+0];
  float r1 = x[d*3+1] - x[s*3+1];
  float r2 = x[d*3+2] - x[s*3+2];
  rij[e*3+0] = r0; rij[e*3+1] = r1; rij[e*3+2] = r2;
  float dist = sqrtf(r0*r0 + r1*r1 + r2*r2);
#pragma unroll
  for (int k = 0; k < RBFK; ++k) {
    float c = (10.0f/15.0f) * (float)k;
    float z = (dist - c) / (0.625f + 1e-12f);
    rbfb[e*RBFK + k] = f2bf(expf(-0.5f * z * z));
  }
}

// ---------------- MFMA bf16 GEMM: 512 threads, BM=128, BN=256, BK=64, single buffer ----------------
// waves 2(row)x4(col), wave tile 64x64, acc 4x4 f32x4
// MODE 0: A bf16 [M][256]
// MODE 1: A = cat(e) = [h[dst] | h[src] | tabE[ie] | rbf | pad] (Kp=832, 2 col-blocks -> C/C2)
// MODE 2: A = [hbf | pmbf] (Kp=512)
// GATE:   no C store; gate[row] = sum_col silu(acc+b1[col]) * gw2[col]  (in-block reduce)
template<int MODE, bool SILU, bool GATE>
__global__ __launch_bounds__(512, 4) void mfma_gemm(
    const unsigned short* __restrict__ A, const unsigned short* __restrict__ A2,
    const unsigned short* __restrict__ Wt,
    const float* __restrict__ bias, const float* __restrict__ bias2,
    unsigned short* __restrict__ C, unsigned short* __restrict__ C2,
    int M, int Kp,
    const unsigned short* __restrict__ hbf, const unsigned short* __restrict__ tabE,
    const int* __restrict__ srcp, const int* __restrict__ dstp, const int* __restrict__ iep,
    const unsigned short* __restrict__ rbfb, const unsigned short* __restrict__ zpad,
    const float* __restrict__ gw2, float* __restrict__ gout) {
  __shared__ unsigned short lds[24576];           // 48KB: As 16KB, Bs 32KB
  unsigned short* As = lds;                       // [128][64] XOR-swizzled
  unsigned short* Bs = lds + 8192;                // [256][64] XOR-swizzled
  const int tid = threadIdx.x;
  const int bn = blockIdx.x * 256;
  const int bm = blockIdx.y * 128;
  const int lane = tid & 63;
  const int w = tid >> 6;          // 0..7
  const int wr = w >> 2;           // 0..1  (64-row band)
  const int wc = w & 3;            // 0..3  (64-col band)
  const int subrow = lane >> 3;                 // 0..7
  const int kd = 8 * ((lane & 7) ^ subrow);     // pre-swizzled source k-offset (elems)

  unsigned int offB[4];
#pragma unroll
  for (int q = 0; q < 4; ++q)
    offB[q] = (unsigned)(bn + w * 32 + q * 8 + subrow) * (unsigned)Kp;

  unsigned int offA[2], offA2[2], offE[2];
#pragma unroll
  for (int q = 0; q < 2; ++q) {
    int m = bm + w * 16 + q * 8 + subrow;
    int mc = (m < M) ? m : (M - 1);
    if (MODE == 1) {
      offA[q]  = (unsigned)dstp[m] * 256u;
      offA2[q] = (unsigned)srcp[m] * 256u;
      offE[q]  = (unsigned)iep[m] * 256u;
    } else {
      offA[q]  = (unsigned)mc * 256u;
      offA2[q] = (unsigned)mc * 256u;
      offE[q]  = 0u;
    }
  }

  const int nt = Kp >> 6;
  f32x4 acc[4][4] = {};

  for (int t = 0; t < nt; ++t) {
    const int k0 = t << 6;
    // stage: A 2 issues/wave, B 4 issues/wave (wave-uniform LDS dest, per-lane global src)
#pragma unroll
    for (int q = 0; q < 2; ++q) {
      const unsigned short* gp;
      if (MODE == 0) {
        gp = A + offA[q] + k0 + kd;
      } else if (MODE == 1) {
        if (k0 < 256)      gp = hbf + offA[q] + k0 + kd;
        else if (k0 < 512) gp = hbf + offA2[q] + (k0 - 256) + kd;
        else if (k0 < 768) gp = tabE + offE[q] + (k0 - 512) + kd;
        else {
          int m = bm + w * 16 + q * 8 + subrow;
          gp = (kd < RBFK) ? (rbfb + m * RBFK + kd) : zpad;
        }
      } else {
        gp = (k0 < 256) ? (A + offA[q] + k0 + kd) : (A2 + offA2[q] + (k0 - 256) + kd);
      }
      gload16(gp, (char*)As + w * 2048 + q * 1024);
    }
#pragma unroll
    for (int q = 0; q < 4; ++q)
      gload16(Wt + offB[q] + k0 + kd, (char*)Bs + w * 4096 + q * 1024);
    __syncthreads();
    // compute: 2 k-slices of 32, 16 MFMA each per wave
#pragma unroll
    for (int ks = 0; ks < 2; ++ks) {
      const int kb = (ks * 64 + ((lane >> 4) << 4)) ^ ((lane & 7) << 4);
      bf16x8 bfv[4];
#pragma unroll
      for (int j = 0; j < 4; ++j)
        bfv[j] = *(const bf16x8*)((const char*)Bs + (wc * 64 + j * 16 + (lane & 15)) * 128 + kb);
#pragma unroll
      for (int i = 0; i < 4; ++i) {
        bf16x8 af = *(const bf16x8*)((const char*)As + (wr * 64 + i * 16 + (lane & 15)) * 128 + kb);
#pragma unroll
        for (int j = 0; j < 4; ++j)
          acc[i][j] = __builtin_amdgcn_mfma_f32_16x16x32_bf16(af, bfv[j], acc[i][j], 0, 0, 0);
      }
    }
    __syncthreads();
  }

  if (GATE) {
    float bcol[4], wcol[4];
#pragma unroll
    for (int j = 0; j < 4; ++j) {
      int col = wc * 64 + j * 16 + (lane & 15);
      bcol[j] = bias[col];
      wcol[j] = gw2[col];
    }
    float* part = (float*)lds;   // [4][128]
#pragma unroll
    for (int i = 0; i < 4; ++i) {
#pragma unroll
      for (int q = 0; q < 4; ++q) {
        float lsum = 0.f;
#pragma unroll
        for (int j = 0; j < 4; ++j)
          lsum += silu_f(acc[i][j][q] + bcol[j]) * wcol[j];
        lsum += __shfl_xor(lsum, 1, 64);
        lsum += __shfl_xor(lsum, 2, 64);
        lsum += __shfl_xor(lsum, 4, 64);
        lsum += __shfl_xor(lsum, 8, 64);
        if ((lane & 15) == 0) {
          int rl = wr * 64 + i * 16 + ((lane >> 4) << 2) + q;
          part[wc * 128 + rl] = lsum;
        }
      }
    }
    __syncthreads();
    if (tid < 128)
      gout[bm + tid] = part[tid] + part[128 + tid] + part[256 + tid] + part[384 + tid];
    return;
  }

  // coalesced C-store: acc -> LDS [128][136] bf16 (two 128-col halves) -> 16B global stores
  const float* biasw = bias;
  unsigned short* Cw = C;
  if (MODE == 1 && bn >= 256) { biasw = bias2; Cw = C2; }

  float bcol[4];
#pragma unroll
  for (int j = 0; j < 4; ++j) bcol[j] = biasw[wc * 64 + j * 16 + (lane & 15)];

  unsigned short* T = lds;   // [128][136]
#pragma unroll
  for (int hh = 0; hh < 2; ++hh) {
    if ((wc >> 1) == hh) {
#pragma unroll
      for (int i = 0; i < 4; ++i)
#pragma unroll
        for (int j = 0; j < 4; ++j)
#pragma unroll
          for (int q = 0; q < 4; ++q) {
            int rl = wr * 64 + i * 16 + ((lane >> 4) << 2) + q;
            int cl = (wc & 1) * 64 + j * 16 + (lane & 15);
            float v = acc[i][j][q] + bcol[j];
            if (SILU) v = silu_f(v);
            T[rl * 136 + cl] = f2bf(v);
          }
    }
    __syncthreads();
#pragma unroll
    for (int it = 0; it < 4; ++it) {
      int row = it * 32 + (tid >> 4);
      int grow = bm + row;
      if (grow < M) {
        uint4 v = *(const uint4*)&T[row * 136 + (tid & 15) * 8];
        *(uint4*)&Cw[(size_t)grow * 256 + hh * 128 + (tid & 15) * 8] = v;
      }
    }
    __syncthreads();
  }
}

// ---------------- CSR gather: pm_sum (bf16 out) + dx + x update ----------------
__global__ void gather_pm_dx(const unsigned short* __restrict__ pm, const float* __restrict__ gate,
                             const float* __restrict__ rij, const int* __restrict__ rowstart,
                             const int* __restrict__ eids, const float* __restrict__ gb2,
                             unsigned short* __restrict__ pmbf, float* __restrict__ x) {
  int n = blockIdx.x, k = threadIdx.x;
  int s = rowstart[n], e1 = rowstart[n + 1];
  float acc = 0.f, dx = 0.f;
  float b2 = gb2[0];
  for (int t = s; t < e1; ++t) {
    int e = eids[t];
    acc += bf2f(pm[(size_t)e*HID + k]);
    if (k < 3) dx += rij[e*3 + k] * (gate[e] + b2);
  }
  pmbf[(size_t)n*HID + k] = f2bf(acc);
  if (k < 3) x[n*3 + k] += dx;
}

// ---------------- LayerNorm(h + u) ----------------
__global__ void ln_kernel(float* __restrict__ h, unsigned short* __restrict__ hbf,
                          const unsigned short* __restrict__ u,
                          const float* __restrict__ g, const float* __restrict__ b) {
  int n = blockIdx.x;
  int k = threadIdx.x;
  int lane = k & 63, wv = k >> 6;
  float z = h[(size_t)n*HID + k] + bf2f(u[(size_t)n*HID + k]);
  __shared__ float red[4];
  __shared__ float s_mu, s_rstd;
  float s = z;
#pragma unroll
  for (int off = 32; off > 0; off >>= 1) s += __shfl_down(s, off, 64);
  if (lane == 0) red[wv] = s;
  __syncthreads();
  if (k == 0) s_mu = (red[0] + red[1] + red[2] + red[3]) * (1.0f/HID);
  __syncthreads();
  float d = z - s_mu;
  float s2 = d * d;
#pragma unroll
  for (int off = 32; off > 0; off >>= 1) s2 += __shfl_down(s2, off, 64);
  if (lane == 0) red[wv] = s2;
  __syncthreads();
  if (k == 0) s_rstd = 1.0f / sqrtf((red[0] + red[1] + red[2] + red[3]) * (1.0f/HID) + 1e-5f);
  __syncthreads();
  float o = d * s_rstd * g[k] + b[k];
  h[(size_t)n*HID + k] = o;
  hbf[(size_t)n*HID + k] = f2bf(o);
}

// ---------------- readout ----------------
__global__ void graph_acc_kernel(const float* __restrict__ h, const int* __restrict__ ng,
                                 float* __restrict__ hg, float* __restrict__ cnt) {
  int n = blockIdx.x, k = threadIdx.x;
  int g = ng[n];
  atomicAdd(&hg[(size_t)g*HID + k], h[(size_t)n*HID + k]);
  if (k == 0) atomicAdd(&cnt[g], 1.0f);
}

__global__ void head_kernel(const float* __restrict__ hg, const float* __restrict__ cnt,
                            const float* __restrict__ head_W, const float* __restrict__ head_b,
                            float* __restrict__ out) {
  int g = threadIdx.x;
  if (g >= NG) return;
  float dot = 0.f;
  for (int k = 0; k < HID; ++k) dot += hg[(size_t)g*HID + k] * head_W[k];
  float c = fmaxf(cnt[g], 1.0f);
  float v = (dot / c + head_b[0]) * 0.5f;
  out[g] = 1.0f / (1.0f + expf(-v));
}

extern "C" void kernel_launch(void* const* d_in, const int* in_sizes, int n_in,
                              void* d_out, int out_size, void* d_ws, size_t ws_size,
                              hipStream_t stream) {
  (void)in_sizes; (void)n_in; (void)out_size; (void)ws_size;
  const float* a_t      = (const float*)d_in[0];
  const float* c_t      = (const float*)d_in[1];
  const float* e_t      = (const float*)d_in[2];
  const float* x_t      = (const float*)d_in[3];
  const float* g_a      = (const float*)d_in[4];
  const float* g_c      = (const float*)d_in[5];
  const float* g_e      = (const float*)d_in[6];
  const float* atom_W   = (const float*)d_in[7];
  const float* charge_W = (const float*)d_in[8];
  const float* bond_W   = (const float*)d_in[9];
  const float* fuse_W   = (const float*)d_in[10];
  const float* fuse_b   = (const float*)d_in[11];
  const float* lift_W   = (const float*)d_in[12];
  const float* lift_b   = (const float*)d_in[13];
  const float* phim_W1  = (const float*)d_in[14];
  const float* phim_b1  = (const float*)d_in[15];
  const float* phim_W2  = (const float*)d_in[16];
  const float* phim_b2  = (const float*)d_in[17];
  const float* phix_W1  = (const float*)d_in[18];
  const float* phix_b1  = (const float*)d_in[19];
  const float* phix_W2  = (const float*)d_in[20];
  const float* phix_b2  = (const float*)d_in[21];
  const float* psim_W1  = (const float*)d_in[22];
  const float* psim_b1  = (const float*)d_in[23];
  const float* psim_W2  = (const float*)d_in[24];
  const float* psim_b2  = (const float*)d_in[25];
  const float* updh_W1  = (const float*)d_in[26];
  const float* updh_b1  = (const float*)d_in[27];
  const float* updh_W2  = (const float*)d_in[28];
  const float* updh_b2  = (const float*)d_in[29];
  const float* ln_g     = (const float*)d_in[30];
  const float* ln_b     = (const float*)d_in[31];
  const float* head_W   = (const float*)d_in[32];
  const float* head_b   = (const float*)d_in[33];
  const int*   src      = (const int*)d_in[34];
  const int*   dst      = (const int*)d_in[35];
  const int*   ngraph   = (const int*)d_in[36];
  float* out = (float*)d_out;

  char* p = (char*)d_ws;
  auto carve = [&](size_t bytes) -> char* {
    char* r = p; p += (bytes + 255) & ~(size_t)255; return r;
  };
  float*          h     = (float*)carve((size_t)NN*HID*4);
  unsigned short* hbf   = (unsigned short*)carve((size_t)NN*HID*2);
  float*          xpos  = (float*)carve((size_t)NN*3*4);
  int*            ie    = (int*)carve((size_t)NE*4);
  float*          tabA  = (float*)carve((size_t)KA*HID*4);
  float*          tabC  = (float*)carve((size_t)KC*HID*4);
  unsigned short* tabE  = (unsigned short*)carve((size_t)KE*HID*2);
  unsigned short* rbfb  = (unsigned short*)carve((size_t)NE*RBFK*2);
  float*          rij   = (float*)carve((size_t)NE*3*4);
  float*          gate  = (float*)carve((size_t)NE*4);
  unsigned short* pmbf  = (unsigned short*)carve((size_t)NN*HID*2);
  unsigned short* zpad  = (unsigned short*)carve(256);
  size_t hg_bytes = (size_t)NG*HID*4 + (size_t)NG*4;
  float*          hg    = (float*)carve(hg_bytes);
  float*          cnt   = hg + (size_t)NG*HID;
  unsigned short* buf0  = (unsigned short*)carve((size_t)NE*HID*2);
  unsigned short* buf1  = (unsigned short*)carve((size_t)NE*HID*2);
  unsigned short* buf2  = (unsigned short*)carve((size_t)NE*HID*2);
  // CSR
  int* deg      = (int*)carve(10240*4);
  int* cursor   = (int*)carve(10240*4);
  int* rowstart = (int*)carve(10241*4);
  int* eids     = (int*)carve((size_t)NE*4);
  // transposed bf16 weights
  unsigned short* wCat   = (unsigned short*)carve((size_t)NDEP*512*CATP*2);
  unsigned short* wPhim2 = (unsigned short*)carve((size_t)NDEP*HID*HID*2);
  unsigned short* wPhix1 = (unsigned short*)carve((size_t)NDEP*HID*HID*2);
  unsigned short* wPsim2 = (unsigned short*)carve((size_t)NDEP*HID*HID*2);
  unsigned short* wUpd1  = (unsigned short*)carve((size_t)NDEP*HID*512*2);
  unsigned short* wUpd2  = (unsigned short*)carve((size_t)NDEP*HID*HID*2);

  // ---- weight conversion ----
  convw_cat<<<dim3(CATP/32, 4, NDEP), 256, 0, stream>>>(phim_W1, wCat, 0);
  convw_cat<<<dim3(CATP/32, 4, NDEP), 256, 0, stream>>>(psim_W1, wCat, 256);
  convw_plain<<<dim3(8, 4, NDEP), 256, 0, stream>>>(phim_W2, wPhim2, 256);
  convw_plain<<<dim3(8, 4, NDEP), 256, 0, stream>>>(phix_W1, wPhix1, 256);
  convw_plain<<<dim3(8, 4, NDEP), 256, 0, stream>>>(psim_W2, wPsim2, 256);
  convw_plain<<<dim3(8, 4, NDEP), 256, 0, stream>>>(updh_W2, wUpd2, 256);
  convw_plain<<<dim3(16, 4, NDEP), 256, 0, stream>>>(updh_W1, wUpd1, 512);
  hipMemsetAsync(zpad, 0, 256, stream);

  tables_kernel<<<KA + KC + KE, 256, 0, stream>>>(atom_W, charge_W, bond_W, fuse_W, fuse_b,
                                                  lift_W, lift_b, tabA, tabC, tabE);
  node_init_kernel<<<NN, 256, 0, stream>>>(a_t, c_t, g_a, g_c, x_t, tabA, tabC, h, hbf, xpos);
  edge_init_kernel<<<(NE + 255)/256, 256, 0, stream>>>(e_t, g_e, ie);

  // ---- CSR build ----
  hipMemsetAsync(deg, 0, 10240*4, stream);
  hist_kernel<<<(NE + 255)/256, 256, 0, stream>>>(dst, deg);
  scan_kernel<<<1, 1024, 0, stream>>>(deg, rowstart, cursor);
  fill_kernel<<<(NE + 255)/256, 256, 0, stream>>>(dst, cursor, eids);
  sortrows_kernel<<<(NN + 255)/256, 256, 0, stream>>>(rowstart, eids);

  dim3 gridCat(2, NE/128);
  dim3 gridE(1, NE/128);
  dim3 gridN(1, (NN + 127)/128);

  for (int d = 0; d < NDEP; ++d) {
    const float* pb1m = phim_b1 + (size_t)d*HID;
    const float* pb2m = phim_b2 + (size_t)d*HID;
    const float* pxb1 = phix_b1 + (size_t)d*HID;
    const float* pxW2 = phix_W2 + (size_t)d*HID;
    const float* pxb2 = phix_b2 + (size_t)d;
    const float* psb1 = psim_b1 + (size_t)d*HID;
    const float* psb2 = psim_b2 + (size_t)d*HID;
    const float* pub1 = updh_b1 + (size_t)d*HID;
    const float* pub2 = updh_b2 + (size_t)d*HID;

    rbf_kernel<<<(NE + 255)/256, 256, 0, stream>>>(xpos, src, dst, rij, rbfb);

    // c1 (buf0), ps1 (buf1) = silu(cat @ [phim_W1 ; psim_W1] + b)
    mfma_gemm<1, true, false><<<gridCat, 512, 0, stream>>>(
        nullptr, nullptr, wCat + (size_t)d*512*CATP, pb1m, psb1, buf0, buf1, NE, CATP,
        hbf, tabE, src, dst, ie, rbfb, zpad, nullptr, nullptr);
    // m (buf2) = silu(c1 @ phim_W2 + b2)
    mfma_gemm<0, true, false><<<gridE, 512, 0, stream>>>(
        buf0, nullptr, wPhim2 + (size_t)d*HID*HID, pb2m, nullptr, buf2, nullptr, NE, HID,
        nullptr, nullptr, nullptr, nullptr, nullptr, nullptr, zpad, nullptr, nullptr);
    // pm (buf0) = silu(ps1 @ psim_W2 + b2)
    mfma_gemm<0, true, false><<<gridE, 512, 0, stream>>>(
        buf1, nullptr, wPsim2 + (size_t)d*HID*HID, psb2, nullptr, buf0, nullptr, NE, HID,
        nullptr, nullptr, nullptr, nullptr, nullptr, nullptr, zpad, nullptr, nullptr);
    // gate = silu(m @ phix_W1 + b1) @ phix_W2   (bias b2 added at use)
    mfma_gemm<0, false, true><<<gridE, 512, 0, stream>>>(
        buf2, nullptr, wPhix1 + (size_t)d*HID*HID, pxb1, nullptr, nullptr, nullptr, NE, HID,
        nullptr, nullptr, nullptr, nullptr, nullptr, nullptr, zpad, pxW2, gate);
    // pm_sum -> pmbf ; x += dx
    gather_pm_dx<<<NN, 256, 0, stream>>>(buf0, gate, rij, rowstart, eids, pxb2, pmbf, xpos);
    // u1 (buf1) = silu([h, pm] @ updh_W1 + b1)
    mfma_gemm<2, true, false><<<gridN, 512, 0, stream>>>(
        hbf, pmbf, wUpd1 + (size_t)d*HID*512, pub1, nullptr, buf1, nullptr, NN, 512,
        nullptr, nullptr, nullptr, nullptr, nullptr, nullptr, zpad, nullptr, nullptr);
    // u (buf2) = u1 @ updh_W2 + b2
    mfma_gemm<0, false, false><<<gridN, 512, 0, stream>>>(
        buf1, nullptr, wUpd2 + (size_t)d*HID*HID, pub2, nullptr, buf2, nullptr, NN, HID,
        nullptr, nullptr, nullptr, nullptr, nullptr, nullptr, zpad, nullptr, nullptr);
    ln_kernel<<<NN, 256, 0, stream>>>(h, hbf, buf2, ln_g + (size_t)d*HID, ln_b + (size_t)d*HID);
  }

  hipMemsetAsync(hg, 0, hg_bytes, stream);
  graph_acc_kernel<<<NN, 256, 0, stream>>>(h, ngraph, hg, cnt);
  head_kernel<<<1, 64, 0, stream>>>(hg, cnt, head_W, head_b, out);
}